// Round 6
// baseline (955.321 us; speedup 1.0000x reference)
//
#include <hip/hip_runtime.h>

#define KBINS  10
#define SBIN   100
#define BETA   0.9f
#define THR    1.0f
#define CDIV(a,b) (((a)+(b)-1)/(b))

// Padded spike layouts (halo: 1 row top/bottom, 1 col left, 7 right):
//   spk1p [1000][ 4][52][192]   spk2p [1000][ 8][27][100]   spk3p [1000][16][15][54]
// Halo bytes actually READ by k_convs2 (audited R4, verified R4/R5 pass):
//   - bottom row H+1: all three buffers
//   - top row 0:      spk2p, spk3p only (L2 has pad_top=0)
//   - col W+1, rows 1..H: all three (pre-zeroed once by k_col_zero)
//   - col 0, cols W+2..W+7, spk1p row 0: NEVER read -> may hold poison.
// R4 lesson: no halo writes inside hot unrolled loops (spill trigger).
// R5 lesson: conv1 widening trades TLP for MLP at a net loss -> R6 deletes
// the L1 conv kernel entirely and fuses it into the scan (x_t is 147 KB,
// L2-resident; 9 FMA/step fits the scan's dep-chain budget).

// ---------------------------------------------------------------------------
// Coalesced zero of full halo rows (u16 chunks). rowOff1 < 0 => one row only.
// ---------------------------------------------------------------------------
__global__ void k_row_zero(unsigned char* __restrict__ base, int planeStride,
                           int rowOff0, int rowOff1, int rowBytes, int nplanes) {
    int half = rowBytes >> 1;
    int per  = (rowOff1 >= 0 ? 2 : 1) * half;
    int n = blockIdx.x * blockDim.x + threadIdx.x;
    if (n >= nplanes * per) return;
    int pl = n / per;
    int r  = n - pl * per;
    int off = (r < half) ? (rowOff0 + 2 * r) : (rowOff1 + 2 * (r - half));
    *(unsigned short*)(base + (size_t)pl * planeStride + off) = 0;
}

// ---------------------------------------------------------------------------
// Zero col W+1 for interior rows 1..H of every plane (the only column halo
// convs2 reads). Done once so the scans stay branch-free.
// ---------------------------------------------------------------------------
__global__ void k_col_zero(unsigned char* __restrict__ base, int planeStride,
                           int Wp, int W, int H, int nplanes) {
    int n = blockIdx.x * blockDim.x + threadIdx.x;
    if (n >= nplanes * H) return;
    int pl = n / H;
    int r  = 1 + (n - pl * H);
    base[(size_t)pl * planeStride + r * Wp + (W + 1)] = 0;
}

// ---------------------------------------------------------------------------
// R6: FUSED layer-1 conv + membrane scan, full 1000 steps, one kernel.
// Thread owns one (c, h, w) of the 4x50x184 output. Per step it computes the
// 3x3 stride-2 conv directly from x (x_t = 147 KB, L2/L3-resident; ~55 cy
// dep chain/step) instead of reading a 147 MB cbuf written by a separate
// conv kernel. Eliminates 147 MB HBM write + ~75 MB HBM read and the whole
// k_conv1 dispatch (95 us) + cold-read scan (~55 us).
// Tap masking, FMA order, and scan update order replicate the deleted
// k_conv1 + k_scan bit-exactly.
// 5-step ping-pong prefetch (2 x 45 tap regs, statically indexed);
// __launch_bounds__(64,1) per the R1/R4 anti-spill lesson.
// ---------------------------------------------------------------------------
#define FS1_LOAD(DST, T0) do {                                                \
    const float* xb_ = x + (size_t)(T0) * 36800;                              \
    _Pragma("unroll")                                                         \
    for (int j = 0; j < 5; j++) {                                             \
        const float* xt_ = xb_ + j * 36800;                                   \
        float2 v0_ = *(const float2*)(xt_ + ro0 + c0);                        \
        float2 v1_ = *(const float2*)(xt_ + ro1 + c0);                        \
        float2 v2_ = *(const float2*)(xt_ + ro2 + c0);                        \
        DST[j][0] = v0_.x; DST[j][1] = v0_.y; DST[j][2] = xt_[ro0 + c2];      \
        DST[j][3] = v1_.x; DST[j][4] = v1_.y; DST[j][5] = xt_[ro1 + c2];      \
        DST[j][6] = v2_.x; DST[j][7] = v2_.y; DST[j][8] = xt_[ro2 + c2];      \
    }                                                                         \
} while (0)

#define FS1_STEPS(SRC, T0) do {                                               \
    _Pragma("unroll")                                                         \
    for (int j = 0; j < 5; j++) {                                             \
        float a_ = bb;                                                        \
        a_ = fmaf(SRC[j][0],       wr0, a_);                                  \
        a_ = fmaf(SRC[j][1],       wr1, a_);                                  \
        a_ = fmaf(SRC[j][2] * cm,  wr2, a_);                                  \
        a_ = fmaf(SRC[j][3],       wr3, a_);                                  \
        a_ = fmaf(SRC[j][4],       wr4, a_);                                  \
        a_ = fmaf(SRC[j][5] * cm,  wr5, a_);                                  \
        a_ = fmaf(SRC[j][6] * rm2, wr6, a_);                                  \
        a_ = fmaf(SRC[j][7] * rm2, wr7, a_);                                  \
        a_ = fmaf(SRC[j][8] * rmcm, wr8, a_);                                 \
        m = fmaf(m, BETA, a_);                                                \
        float spv_ = (m - THR > 0.0f) ? 1.0f : 0.0f;                          \
        m -= spv_ * THR;                                                      \
        sp[(size_t)((T0) + j) * 39936] = (unsigned char)spv_;                 \
        s += m;                                                               \
        q = fmaf(m, m, q);                                                    \
    }                                                                         \
} while (0)

__global__ void __launch_bounds__(64, 1)
k_fscan1(const float* __restrict__ x,
         const float* __restrict__ w1,
         const float* __restrict__ b1,
         unsigned char* __restrict__ spk,
         float* __restrict__ skip,
         float* __restrict__ mscratch) {
    int p = blockIdx.x * blockDim.x + threadIdx.x;
    if (p >= 36800) return;
    int c  = p / 9200;
    int hw = p - c * 9200;
    int h  = hw / 184, w = hw - h * 184;

    // conv geometry (identical to deleted k_conv1 semantics)
    float rm2  = (h < 49) ? 1.f : 0.f;
    float cm   = (2 * w + 2 <= 367) ? 1.f : 0.f;
    float rmcm = rm2 * cm;
    int ro0 = (2 * h) * 368;
    int ro1 = ro0 + 368;
    int ro2 = min(2 * h + 2, 99) * 368;
    int c0  = 2 * w;
    int c2  = min(2 * w + 2, 367);

    float wr0 = w1[c * 9 + 0], wr1 = w1[c * 9 + 1], wr2 = w1[c * 9 + 2];
    float wr3 = w1[c * 9 + 3], wr4 = w1[c * 9 + 4], wr5 = w1[c * 9 + 5];
    float wr6 = w1[c * 9 + 6], wr7 = w1[c * 9 + 7], wr8 = w1[c * 9 + 8];
    float bb  = b1[c];

    unsigned char* sp = spk + (size_t)c * 9984 + (h + 1) * 192 + (w + 1);

    float m = 0.0f;
    float A[5][9], B[5][9];
    FS1_LOAD(A, 0);

    for (int k = 0; k < KBINS; k++) {
        float s = 0.0f, q = 0.0f;
        for (int gp = 0; gp < 10; gp++) {
            int tA = k * SBIN + gp * 10;
            FS1_LOAD(B, tA + 5);            // tA+5 <= 995: always valid
            FS1_STEPS(A, tA);
            if (tA + 10 < 1000) FS1_LOAD(A, tA + 10);   // uniform branch
            FS1_STEPS(B, tA + 5);
        }
        float mean = s * (1.0f / SBIN);
        float var  = q * (1.0f / SBIN) - mean * mean;
        float sd   = sqrtf(fmaxf(var, 1e-8f));
        skip[(size_t)(k * 8 + c) * 9200 + hw]       = mean;
        skip[(size_t)(k * 8 + 4 + c) * 9200 + hw]   = sd;
    }
    mscratch[p] = m;
}

// ---------------------------------------------------------------------------
// Membrane scan (layers 2-4), full 1000 steps. PF=50 ping-pong register
// double-buffer. __launch_bounds__(64,1): thread-starved kernel; default
// occupancy-targeted regalloc spills the 50-float buffers (R1). Exact R2
// body (u8 stores only — R4's in-loop edge-u16 variant re-spilled).
// ---------------------------------------------------------------------------
__global__ void __launch_bounds__(64, 1)
k_scan(const float* __restrict__ cbuf,
       unsigned char* __restrict__ spk,
       float* __restrict__ skip,
       float* __restrict__ mscratch,
       int C, int HW, int Win, int Wp, int HpWp, int write_spk) {
    const int PF = 50;
    int CHW = C * HW;
    int p = blockIdx.x * blockDim.x + threadIdx.x;
    if (p >= CHW) return;
    int c  = p / HW;
    int hw = p - c * HW;
    int h  = hw / Win, w = hw - h * Win;

    const size_t tstr = (size_t)C * HpWp;
    unsigned char* sp = spk + (size_t)c * HpWp + (h + 1) * Wp + (w + 1);

    float m = 0.0f;
    float va[PF], vb[PF];
    #pragma unroll
    for (int j = 0; j < PF; j++) va[j] = cbuf[(size_t)j * CHW + p];

    for (int k = 0; k < KBINS; k++) {
        float s = 0.0f, q = 0.0f;

        {
            int tn = k * SBIN + PF;
            #pragma unroll
            for (int j = 0; j < PF; j++)
                vb[j] = cbuf[(size_t)(tn + j) * CHW + p];
            #pragma unroll
            for (int j = 0; j < PF; j++) {
                m = fmaf(m, BETA, va[j]);
                float spv = (m - THR > 0.0f) ? 1.0f : 0.0f;
                m -= spv * THR;
                if (write_spk) sp[(size_t)(k * SBIN + j) * tstr] = (unsigned char)spv;
                s += m;
                q = fmaf(m, m, q);
            }
        }
        {
            int tn = (k + 1) * SBIN;
            bool more = (k + 1 < KBINS);
            #pragma unroll
            for (int j = 0; j < PF; j++)
                va[j] = more ? cbuf[(size_t)(tn + j) * CHW + p] : 0.0f;
            #pragma unroll
            for (int j = 0; j < PF; j++) {
                m = fmaf(m, BETA, vb[j]);
                float spv = (m - THR > 0.0f) ? 1.0f : 0.0f;
                m -= spv * THR;
                if (write_spk) sp[(size_t)(k * SBIN + PF + j) * tstr] = (unsigned char)spv;
                s += m;
                q = fmaf(m, m, q);
            }
        }

        float mean = s * (1.0f / SBIN);
        float var  = q * (1.0f / SBIN) - mean * mean;
        float sd   = sqrtf(fmaxf(var, 1e-8f));
        skip[(size_t)(k * 2 * C + c) * HW + hw]     = mean;
        skip[(size_t)(k * 2 * C + C + c) * HW + hw] = sd;
    }
    mscratch[p] = m;
}

// ---------------------------------------------------------------------------
// Stride-2 time-conv from padded u8 spikes, OW outputs/thread, COG couts.
// ---------------------------------------------------------------------------
template<int CIN, int COUT, int COG, int OW,
         int HOUT, int WOUT, int PADH, int HP, int WP>
__global__ void k_convs2(const unsigned char* __restrict__ spk,
                         const float* __restrict__ wt,
                         const float* __restrict__ bias,
                         float* __restrict__ out) {
    const int WQ = (WOUT + OW - 1) / OW;
    const int NT = 2 * OW + 1;
    int n = blockIdx.x * blockDim.x + threadIdx.x;
    if (n >= 1000 * HOUT * WQ) return;
    int wq  = n % WQ;
    int tmp = n / WQ;
    int h   = tmp % HOUT;
    int t   = tmp / HOUT;
    int cog = blockIdx.y;
    int w0  = wq * OW;

    const unsigned char* base = spk + (size_t)t * CIN * HP * WP
                              + (2 * h - PADH + 1) * WP + (2 * w0 + 1);

    float acc[OW][COG];
    #pragma unroll
    for (int q = 0; q < OW; q++)
        #pragma unroll
        for (int co = 0; co < COG; co++) acc[q][co] = bias[cog * COG + co];

    for (int ci = 0; ci < CIN; ci++) {
        const unsigned char* ic = base + (size_t)ci * HP * WP;
        float tap[3][NT];
        #pragma unroll
        for (int r = 0; r < 3; r++)
            #pragma unroll
            for (int j = 0; j < NT; j++)
                tap[r][j] = (float)ic[r * WP + j];
        #pragma unroll
        for (int co = 0; co < COG; co++) {
            const float* wc = wt + ((size_t)(cog * COG + co) * CIN + ci) * 9;
            #pragma unroll
            for (int r = 0; r < 3; r++)
                #pragma unroll
                for (int kw = 0; kw < 3; kw++) {
                    float wv = wc[r * 3 + kw];
                    #pragma unroll
                    for (int q = 0; q < OW; q++)
                        acc[q][co] = fmaf(tap[r][2 * q + kw], wv, acc[q][co]);
                }
        }
    }

    float* ot = out + ((size_t)t * COUT + cog * COG) * (HOUT * WOUT) + h * WOUT + w0;
    #pragma unroll
    for (int co = 0; co < COG; co++) {
        float* oc = ot + (size_t)co * (HOUT * WOUT);
        if constexpr (OW == 4) {
            *(float4*)oc = make_float4(acc[0][co], acc[1][co], acc[2][co], acc[3][co]);
        } else {
            if (w0 + 2 <= WOUT) *(float2*)oc = make_float2(acc[0][co], acc[1][co]);
            else                oc[0] = acc[0][co];
        }
    }
}

// ---------------------------------------------------------------------------
// Bilinear upsample (JAX half-pixel, edge-clamp) + channel concat.
// ---------------------------------------------------------------------------
__global__ void k_up_cat(const float* __restrict__ up_src, int Cup, int Hi, int Wi,
                         const float* __restrict__ skip, int Cskip,
                         float* __restrict__ out, int Ho, int Wo) {
    int total = (Cup + Cskip) * Ho * Wo;
    int n = blockIdx.x * blockDim.x + threadIdx.x;
    if (n >= total) return;
    int w   = n % Wo;
    int tmp = n / Wo;
    int h   = tmp % Ho;
    int c   = tmp / Ho;
    float v;
    if (c < Cup) {
        float ph = (h + 0.5f) * (float)Hi / (float)Ho - 0.5f;
        float pw = (w + 0.5f) * (float)Wi / (float)Wo - 0.5f;
        float fh = floorf(ph), fw = floorf(pw);
        int h0 = (int)fh, w0 = (int)fw;
        float ah = ph - fh, aw = pw - fw;
        int h0c = min(max(h0, 0), Hi - 1), h1c = min(max(h0 + 1, 0), Hi - 1);
        int w0c = min(max(w0, 0), Wi - 1), w1c = min(max(w0 + 1, 0), Wi - 1);
        const float* sc = up_src + (size_t)c * Hi * Wi;
        float v00 = sc[h0c * Wi + w0c], v01 = sc[h0c * Wi + w1c];
        float v10 = sc[h1c * Wi + w0c], v11 = sc[h1c * Wi + w1c];
        v = (1.0f - ah) * ((1.0f - aw) * v00 + aw * v01)
          + ah * ((1.0f - aw) * v10 + aw * v11);
    } else {
        v = skip[(size_t)(c - Cup) * Ho * Wo + h * Wo + w];
    }
    out[n] = v;
}

// ---------------------------------------------------------------------------
// Decoder split-K conv, TEMPLATED: CS channels/chunk, COG couts/thread.
// ---------------------------------------------------------------------------
template<int CIN, int CS, int COG>
__global__ void k_dconv(const float* __restrict__ in,
                        const float* __restrict__ wt,
                        float* __restrict__ part,
                        int Cout, int H, int W) {
    int HW  = H * W;
    int pix = blockIdx.x * blockDim.x + threadIdx.x;
    if (pix >= HW) return;
    int co0   = blockIdx.y * COG;
    int chunk = blockIdx.z;
    int h = pix / W, w = pix - h * W;

    int off[9]; float msk[9];
    #pragma unroll
    for (int kh = 0; kh < 3; kh++) {
        int r = h + kh - 1;
        bool rok = (r >= 0) && (r < H);
        int rc = rok ? r : 0;
        #pragma unroll
        for (int kw = 0; kw < 3; kw++) {
            int cc = w + kw - 1;
            bool cok = (cc >= 0) && (cc < W);
            int ccc = cok ? cc : 0;
            off[kh * 3 + kw] = rc * W + ccc;
            msk[kh * 3 + kw] = (rok && cok) ? 1.0f : 0.0f;
        }
    }

    const float* ibase = in + (size_t)chunk * CS * HW;
    const float* wbase = wt + ((size_t)co0 * CIN + (size_t)chunk * CS) * 9;

    float acc[COG];
    #pragma unroll
    for (int co = 0; co < COG; co++) acc[co] = 0.0f;

    #pragma unroll 8
    for (int ci = 0; ci < CS; ci++) {
        const float* ic = ibase + (size_t)ci * HW;
        float tap[9];
        #pragma unroll
        for (int j = 0; j < 9; j++)
            tap[j] = msk[j] * ic[off[j]];
        #pragma unroll
        for (int co = 0; co < COG; co++) {
            const float* wc = wbase + ((size_t)co * CIN + ci) * 9;
            #pragma unroll
            for (int j = 0; j < 9; j++)
                acc[co] = fmaf(tap[j], wc[j], acc[co]);
        }
    }

    float* pp = part + ((size_t)chunk * Cout + co0) * HW + pix;
    #pragma unroll
    for (int co = 0; co < COG; co++) pp[(size_t)co * HW] = acc[co];
}

__global__ void k_reduce_relu(const float* __restrict__ part,
                              const float* __restrict__ bias,
                              float* __restrict__ out,
                              int Cout, int HW, int nchunks) {
    int n = blockIdx.x * blockDim.x + threadIdx.x;
    if (n >= Cout * HW) return;
    int co = n / HW;
    float acc = bias[co];
    for (int c = 0; c < nchunks; c++)
        acc += part[(size_t)c * Cout * HW + n];
    out[n] = fmaxf(acc, 0.0f);
}

// ---------------------------------------------------------------------------
// Final: bilinear up d1 (post-ReLU) [8,50,184] -> (100,368), fused 1x1 conv.
// ---------------------------------------------------------------------------
__global__ void k_final(const float* __restrict__ d1,
                        const float* __restrict__ wo,
                        const float* __restrict__ bo,
                        float* __restrict__ out) {
    int n = blockIdx.x * blockDim.x + threadIdx.x;
    if (n >= 36800) return;
    int w = n % 368, h = n / 368;
    float ph = (h + 0.5f) * 0.5f - 0.5f;
    float pw = (w + 0.5f) * 0.5f - 0.5f;
    float fh = floorf(ph), fw = floorf(pw);
    int h0 = (int)fh, w0 = (int)fw;
    float ah = ph - fh, aw = pw - fw;
    int h0c = min(max(h0, 0), 49),  h1c = min(max(h0 + 1, 0), 49);
    int w0c = min(max(w0, 0), 183), w1c = min(max(w0 + 1, 0), 183);
    float acc = bo[0];
    #pragma unroll
    for (int c = 0; c < 8; c++) {
        const float* sc = d1 + c * 9200;
        float v00 = sc[h0c * 184 + w0c], v01 = sc[h0c * 184 + w1c];
        float v10 = sc[h1c * 184 + w0c], v11 = sc[h1c * 184 + w1c];
        float v = (1.0f - ah) * ((1.0f - aw) * v00 + aw * v01)
                + ah * ((1.0f - aw) * v10 + aw * v11);
        acc = fmaf(wo[c], v, acc);
    }
    out[n] = acc;
}

// ---------------------------------------------------------------------------
extern "C" void kernel_launch(void* const* d_in, const int* in_sizes, int n_in,
                              void* d_out, int out_size, void* d_ws, size_t ws_size,
                              hipStream_t stream) {
    (void)in_sizes; (void)n_in; (void)out_size; (void)ws_size;
    const float* x   = (const float*)d_in[0];
    const float* w1  = (const float*)d_in[1];
    const float* b1  = (const float*)d_in[2];
    const float* w2  = (const float*)d_in[3];
    const float* b2  = (const float*)d_in[4];
    const float* w3  = (const float*)d_in[5];
    const float* b3  = (const float*)d_in[6];
    const float* w4  = (const float*)d_in[7];
    const float* b4  = (const float*)d_in[8];
    const float* dw4 = (const float*)d_in[9];
    const float* db4 = (const float*)d_in[10];
    const float* dw3 = (const float*)d_in[11];
    const float* db3 = (const float*)d_in[12];
    const float* dw2 = (const float*)d_in[13];
    const float* db2 = (const float*)d_in[14];
    const float* dw1 = (const float*)d_in[15];
    const float* db1 = (const float*)d_in[16];
    const float* wo  = (const float*)d_in[17];
    const float* bo  = (const float*)d_in[18];
    float* out = (float*)d_out;

    // ---- workspace ----
    char* ws = (char*)d_ws;
    size_t off = 0;
    auto alloc = [&](size_t bytes) -> void* {
        void* p = ws + off;
        off += (bytes + 255) & ~(size_t)255;
        return p;
    };
    float*         cbuf  = (float*)alloc(147200000);          // conv buffer (L2+ only now)
    unsigned char* spk1p = (unsigned char*)alloc(39936000);   // [1000,4,52,192]
    unsigned char* spk2p = (unsigned char*)alloc(21600000);   // [1000,8,27,100]
    unsigned char* spk3p = (unsigned char*)alloc(12960000);   // [1000,16,15,54]
    float*         skip0 = (float*)alloc(2944000);            // [80,9200]
    float*         skip1 = (float*)alloc(1472000);            // [160,2300]
    float*         skip2 = (float*)alloc(765440);             // [320,598]
    float*         skip3 = (float*)alloc(412160);             // [640,161]
    float*         msS   = (float*)alloc(147200);             // scan scratch
    // decoder buffers alias cbuf (dead after encoder)
    char* dec = (char*)cbuf;
    size_t doff = 0;
    auto dalloc = [&](size_t bytes) -> void* {
        void* p = dec + doff;
        doff += (bytes + 255) & ~(size_t)255;
        return p;
    };
    float* d4   = (float*)dalloc(10304u * 4);                 // [64,161] post-ReLU
    float* d3   = (float*)dalloc(19136u * 4);                 // [32,598]
    float* d2   = (float*)dalloc(36800u * 4);                 // [16,2300]
    float* d1   = (float*)dalloc(73600u * 4);                 // [8,9200]
    float* cat3 = (float*)dalloc(229632u * 4);                // [384,598]
    float* cat2 = (float*)dalloc(441600u * 4);                // [192,2300]
    float* cat1 = (float*)dalloc(883200u * 4);                // [96,9200]
    float* part = (float*)dalloc(230400u * 4);                // split-K partials

    const int BS  = 256;
    const int SBS = 64;

    // halo zeroing (once, outside the hot kernels):
    //   rows (coalesced u16): spk1p row 51; spk2p rows 0,26; spk3p rows 0,14
    //   col W+1, rows 1..H (scattered bytes, ~608K total)
    k_row_zero<<<CDIV(4000  *  96, BS), BS, 0, stream>>>(spk1p, 9984, 51 * 192, -1,   192, 4000);
    k_row_zero<<<CDIV(8000  * 100, BS), BS, 0, stream>>>(spk2p, 2700, 0,        2600, 100, 8000);
    k_row_zero<<<CDIV(16000 *  54, BS), BS, 0, stream>>>(spk3p,  810, 0,        756,  54,  16000);
    k_col_zero<<<CDIV(4000  *  50, BS), BS, 0, stream>>>(spk1p, 9984, 192, 184, 50, 4000);
    k_col_zero<<<CDIV(8000  *  25, BS), BS, 0, stream>>>(spk2p, 2700, 100,  92, 25, 8000);
    k_col_zero<<<CDIV(16000 *  13, BS), BS, 0, stream>>>(spk3p,  810,  54,  46, 13, 16000);

    // ---- encoder ----
    // L1: fused conv+scan straight from x (no cbuf round-trip)
    k_fscan1<<<CDIV(36800, SBS), SBS, 0, stream>>>(x, w1, b1, spk1p, skip0, msS);

    k_convs2<4, 8, 8, 4, 25, 92, 0, 52, 192>
        <<<dim3(CDIV(1000 * 25 * 23, BS), 1), BS, 0, stream>>>(spk1p, w2, b2, cbuf);
    k_scan<<<CDIV(18400, SBS), SBS, 0, stream>>>(cbuf, spk2p, skip1, msS,
                                                 8, 2300, 92, 100, 27 * 100, 1);

    k_convs2<8, 16, 16, 2, 13, 46, 1, 27, 100>
        <<<dim3(CDIV(1000 * 13 * 23, BS), 1), BS, 0, stream>>>(spk2p, w3, b3, cbuf);
    k_scan<<<CDIV(9568, SBS), SBS, 0, stream>>>(cbuf, spk3p, skip2, msS,
                                                16, 598, 46, 54, 15 * 54, 1);

    k_convs2<16, 32, 16, 2, 7, 23, 1, 15, 54>
        <<<dim3(CDIV(1000 * 7 * 12, BS), 2), BS, 0, stream>>>(spk3p, w4, b4, cbuf);
    k_scan<<<CDIV(5152, SBS), SBS, 0, stream>>>(cbuf, spk1p /*unused*/, skip3, msS,
                                                32, 161, 23, 31, 9 * 31, 0);

    // ---- decoder: up_cat + templated split-K conv + reduce ----
    {   // L4: skip3[640,7,23] -> d4[64,161]; CS=32 (20 chunks), COG=4
        dim3 g(CDIV(161, 64), 16, 20);
        k_dconv<640, 32, 4><<<g, 64, 0, stream>>>(skip3, dw4, part, 64, 7, 23);
        k_reduce_relu<<<CDIV(64 * 161, BS), BS, 0, stream>>>(part, db4, d4, 64, 161, 20);
    }
    {   // L3: cat3=[up(d4),64|skip2,320] -> d3[32,598]; CS=32 (12), COG=4
        k_up_cat<<<CDIV(384 * 598, BS), BS, 0, stream>>>(d4, 64, 7, 23,
                                                         skip2, 320, cat3, 13, 46);
        dim3 g(CDIV(598, 64), 8, 12);
        k_dconv<384, 32, 4><<<g, 64, 0, stream>>>(cat3, dw3, part, 32, 13, 46);
        k_reduce_relu<<<CDIV(32 * 598, BS), BS, 0, stream>>>(part, db3, d3, 32, 598, 12);
    }
    {   // L2: cat2=[up(d3),32|skip1,160] -> d2[16,2300]; CS=32 (6), COG=4
        k_up_cat<<<CDIV(192 * 2300, BS), BS, 0, stream>>>(d3, 32, 13, 46,
                                                          skip1, 160, cat2, 25, 92);
        dim3 g(CDIV(2300, 128), 4, 6);
        k_dconv<192, 32, 4><<<g, 128, 0, stream>>>(cat2, dw2, part, 16, 25, 92);
        k_reduce_relu<<<CDIV(16 * 2300, BS), BS, 0, stream>>>(part, db2, d2, 16, 2300, 6);
    }
    {   // L1: cat1=[up(d2),16|skip0,80] -> d1[8,9200]; CS=32 (3), COG=4
        k_up_cat<<<CDIV(96 * 9200, BS), BS, 0, stream>>>(d2, 16, 25, 92,
                                                         skip0, 80, cat1, 50, 184);
        dim3 g(CDIV(9200, BS), 2, 3);
        k_dconv<96, 32, 4><<<g, BS, 0, stream>>>(cat1, dw1, part, 8, 50, 184);
        k_reduce_relu<<<CDIV(8 * 9200, BS), BS, 0, stream>>>(part, db1, d1, 8, 9200, 3);
    }
    k_final<<<CDIV(36800, BS), BS, 0, stream>>>(d1, wo, bo, out);
}

// Round 7
// 822.987 us; speedup vs baseline: 1.1608x; 1.1608x over previous
//
#include <hip/hip_runtime.h>

#define KBINS  10
#define SBIN   100
#define BETA   0.9f
#define THR    1.0f
#define CDIV(a,b) (((a)+(b)-1)/(b))

// Padded spike layouts (halo zeros: 1 row top/bottom, 1 col left, 7 right):
//   spk1p [1000][ 4][52][192]   spk2p [1000][ 8][27][100]   spk3p [1000][16][15][54]
// R7 ledger of cross-round lessons:
//  - Zeroing: ONE contiguous 74.5 MB float4 fill (~11 us at 6.8 TB/s, R0) beats
//    every "clever" halo-subset zero tried in R1/R4/R5 — scattered byte stores
//    are partial-line RMWs, ~8x the effective traffic. Transactions, not bytes.
//  - Scan: PF=50 ping-pong + __launch_bounds__(64,1). Without LB the allocator
//    targets occupancy and spills both 50-float buffers (R1: WRITE 75->168 MB).
//    Body must stay branch-free u8 stores (R4's edge-u16 variant re-spilled).
//    Measured ~46 us for L1 (R6-R5 dispatch arithmetic).
//  - conv1: 4-wide/4-cout is the best of {4w scalar, 4w float4, 8w float4}
//    (93-95 us; 8w traded occupancy 72->46% for MLP at a net loss; fusion into
//    the scan spilled + L2-latency-serialized at 230 us). Plateau ~2.4 TB/s.

// ---------------------------------------------------------------------------
__global__ void k_zero16(float4* __restrict__ p, int n16) {
    int i = blockIdx.x * blockDim.x + threadIdx.x;
    if (i < n16) p[i] = make_float4(0.f, 0.f, 0.f, 0.f);
}

// ---------------------------------------------------------------------------
// Layer-1 conv, full T: 4 outputs (w) per thread, 4 couts. (R3 body — the
// compiler emits dwordx4 for the contiguous taps; verified identical perf
// to scalar-tap R0 version.)
// ---------------------------------------------------------------------------
__global__ void k_conv1(const float* __restrict__ x,
                        const float* __restrict__ w1,
                        const float* __restrict__ b1,
                        float* __restrict__ c1) {
    int n = blockIdx.x * blockDim.x + threadIdx.x;
    if (n >= 1000 * 50 * 46) return;
    int wq  = n % 46;
    int tmp = n / 46;
    int h   = tmp % 50;
    int t   = tmp / 50;
    int w0  = wq * 4;

    const float* xt = x + (size_t)t * 36800;
    float rm2 = (h  < 49)  ? 1.f : 0.f;
    float cm8 = (w0 < 180) ? 1.f : 0.f;
    int   r2  = min(2 * h + 2, 99);
    int   cb  = 2 * w0;
    int   c8  = min(cb + 8, 367);

    const float* row0 = xt + (2 * h) * 368 + cb;
    const float* row1 = row0 + 368;
    const float* row2 = xt + r2 * 368 + cb;

    float tap[3][9];
    {
        float4 a = *(const float4*)(row0);
        float4 b = *(const float4*)(row0 + 4);
        tap[0][0] = a.x; tap[0][1] = a.y; tap[0][2] = a.z; tap[0][3] = a.w;
        tap[0][4] = b.x; tap[0][5] = b.y; tap[0][6] = b.z; tap[0][7] = b.w;
    }
    {
        float4 a = *(const float4*)(row1);
        float4 b = *(const float4*)(row1 + 4);
        tap[1][0] = a.x; tap[1][1] = a.y; tap[1][2] = a.z; tap[1][3] = a.w;
        tap[1][4] = b.x; tap[1][5] = b.y; tap[1][6] = b.z; tap[1][7] = b.w;
    }
    {
        float4 a = *(const float4*)(row2);
        float4 b = *(const float4*)(row2 + 4);
        tap[2][0] = a.x * rm2; tap[2][1] = a.y * rm2;
        tap[2][2] = a.z * rm2; tap[2][3] = a.w * rm2;
        tap[2][4] = b.x * rm2; tap[2][5] = b.y * rm2;
        tap[2][6] = b.z * rm2; tap[2][7] = b.w * rm2;
    }
    tap[0][8] = xt[(2 * h) * 368 + c8] * cm8;
    tap[1][8] = xt[(2 * h + 1) * 368 + c8] * cm8;
    tap[2][8] = xt[r2 * 368 + c8] * (rm2 * cm8);

    float* ot = c1 + (size_t)t * 36800 + h * 184 + w0;
    #pragma unroll
    for (int co = 0; co < 4; co++) {
        float b = b1[co];
        float a0 = b, a1 = b, a2 = b, a3 = b;
        #pragma unroll
        for (int r = 0; r < 3; r++) {
            #pragma unroll
            for (int kw = 0; kw < 3; kw++) {
                float wv = w1[co * 9 + r * 3 + kw];
                a0 = fmaf(tap[r][0 + kw], wv, a0);
                a1 = fmaf(tap[r][2 + kw], wv, a1);
                a2 = fmaf(tap[r][4 + kw], wv, a2);
                a3 = fmaf(tap[r][6 + kw], wv, a3);
            }
        }
        *(float4*)(ot + (size_t)co * 9200) = make_float4(a0, a1, a2, a3);
    }
}

// ---------------------------------------------------------------------------
// Membrane scan, full 1000 steps. PF=50 ping-pong register double-buffer.
// __launch_bounds__(64,1): thread-starved kernel (0.5-2.25 waves/CU), so
// occupancy-targeted regalloc is worthless and spills (R1). Exact R2 body.
// ---------------------------------------------------------------------------
__global__ void __launch_bounds__(64, 1)
k_scan(const float* __restrict__ cbuf,
       unsigned char* __restrict__ spk,
       float* __restrict__ skip,
       float* __restrict__ mscratch,
       int C, int HW, int Win, int Wp, int HpWp, int write_spk) {
    const int PF = 50;
    int CHW = C * HW;
    int p = blockIdx.x * blockDim.x + threadIdx.x;
    if (p >= CHW) return;
    int c  = p / HW;
    int hw = p - c * HW;
    int h  = hw / Win, w = hw - h * Win;

    const size_t tstr = (size_t)C * HpWp;
    unsigned char* sp = spk + (size_t)c * HpWp + (h + 1) * Wp + (w + 1);

    float m = 0.0f;
    float va[PF], vb[PF];
    #pragma unroll
    for (int j = 0; j < PF; j++) va[j] = cbuf[(size_t)j * CHW + p];

    for (int k = 0; k < KBINS; k++) {
        float s = 0.0f, q = 0.0f;

        // half A: prefetch t = k*100+50 .. +99 into vb, compute va
        {
            int tn = k * SBIN + PF;
            #pragma unroll
            for (int j = 0; j < PF; j++)
                vb[j] = cbuf[(size_t)(tn + j) * CHW + p];
            #pragma unroll
            for (int j = 0; j < PF; j++) {
                m = fmaf(m, BETA, va[j]);
                float spv = (m - THR > 0.0f) ? 1.0f : 0.0f;
                m -= spv * THR;
                if (write_spk) sp[(size_t)(k * SBIN + j) * tstr] = (unsigned char)spv;
                s += m;
                q = fmaf(m, m, q);
            }
        }
        // half B: prefetch next bin's first half into va, compute vb
        {
            int tn = (k + 1) * SBIN;
            bool more = (k + 1 < KBINS);
            #pragma unroll
            for (int j = 0; j < PF; j++)
                va[j] = more ? cbuf[(size_t)(tn + j) * CHW + p] : 0.0f;
            #pragma unroll
            for (int j = 0; j < PF; j++) {
                m = fmaf(m, BETA, vb[j]);
                float spv = (m - THR > 0.0f) ? 1.0f : 0.0f;
                m -= spv * THR;
                if (write_spk) sp[(size_t)(k * SBIN + PF + j) * tstr] = (unsigned char)spv;
                s += m;
                q = fmaf(m, m, q);
            }
        }

        float mean = s * (1.0f / SBIN);
        float var  = q * (1.0f / SBIN) - mean * mean;
        float sd   = sqrtf(fmaxf(var, 1e-8f));
        skip[(size_t)(k * 2 * C + c) * HW + hw]     = mean;
        skip[(size_t)(k * 2 * C + C + c) * HW + hw] = sd;
    }
    mscratch[p] = m;
}

// ---------------------------------------------------------------------------
// Stride-2 time-conv from padded u8 spikes, OW outputs/thread, COG couts.
// ---------------------------------------------------------------------------
template<int CIN, int COUT, int COG, int OW,
         int HOUT, int WOUT, int PADH, int HP, int WP>
__global__ void k_convs2(const unsigned char* __restrict__ spk,
                         const float* __restrict__ wt,
                         const float* __restrict__ bias,
                         float* __restrict__ out) {
    const int WQ = (WOUT + OW - 1) / OW;
    const int NT = 2 * OW + 1;
    int n = blockIdx.x * blockDim.x + threadIdx.x;
    if (n >= 1000 * HOUT * WQ) return;
    int wq  = n % WQ;
    int tmp = n / WQ;
    int h   = tmp % HOUT;
    int t   = tmp / HOUT;
    int cog = blockIdx.y;
    int w0  = wq * OW;

    const unsigned char* base = spk + (size_t)t * CIN * HP * WP
                              + (2 * h - PADH + 1) * WP + (2 * w0 + 1);

    float acc[OW][COG];
    #pragma unroll
    for (int q = 0; q < OW; q++)
        #pragma unroll
        for (int co = 0; co < COG; co++) acc[q][co] = bias[cog * COG + co];

    for (int ci = 0; ci < CIN; ci++) {
        const unsigned char* ic = base + (size_t)ci * HP * WP;
        float tap[3][NT];
        #pragma unroll
        for (int r = 0; r < 3; r++)
            #pragma unroll
            for (int j = 0; j < NT; j++)
                tap[r][j] = (float)ic[r * WP + j];
        #pragma unroll
        for (int co = 0; co < COG; co++) {
            const float* wc = wt + ((size_t)(cog * COG + co) * CIN + ci) * 9;
            #pragma unroll
            for (int r = 0; r < 3; r++)
                #pragma unroll
                for (int kw = 0; kw < 3; kw++) {
                    float wv = wc[r * 3 + kw];
                    #pragma unroll
                    for (int q = 0; q < OW; q++)
                        acc[q][co] = fmaf(tap[r][2 * q + kw], wv, acc[q][co]);
                }
        }
    }

    float* ot = out + ((size_t)t * COUT + cog * COG) * (HOUT * WOUT) + h * WOUT + w0;
    #pragma unroll
    for (int co = 0; co < COG; co++) {
        float* oc = ot + (size_t)co * (HOUT * WOUT);
        if constexpr (OW == 4) {
            *(float4*)oc = make_float4(acc[0][co], acc[1][co], acc[2][co], acc[3][co]);
        } else {
            if (w0 + 2 <= WOUT) *(float2*)oc = make_float2(acc[0][co], acc[1][co]);
            else                oc[0] = acc[0][co];
        }
    }
}

// ---------------------------------------------------------------------------
// Bilinear upsample (JAX half-pixel, edge-clamp) + channel concat.
// ---------------------------------------------------------------------------
__global__ void k_up_cat(const float* __restrict__ up_src, int Cup, int Hi, int Wi,
                         const float* __restrict__ skip, int Cskip,
                         float* __restrict__ out, int Ho, int Wo) {
    int total = (Cup + Cskip) * Ho * Wo;
    int n = blockIdx.x * blockDim.x + threadIdx.x;
    if (n >= total) return;
    int w   = n % Wo;
    int tmp = n / Wo;
    int h   = tmp % Ho;
    int c   = tmp / Ho;
    float v;
    if (c < Cup) {
        float ph = (h + 0.5f) * (float)Hi / (float)Ho - 0.5f;
        float pw = (w + 0.5f) * (float)Wi / (float)Wo - 0.5f;
        float fh = floorf(ph), fw = floorf(pw);
        int h0 = (int)fh, w0 = (int)fw;
        float ah = ph - fh, aw = pw - fw;
        int h0c = min(max(h0, 0), Hi - 1), h1c = min(max(h0 + 1, 0), Hi - 1);
        int w0c = min(max(w0, 0), Wi - 1), w1c = min(max(w0 + 1, 0), Wi - 1);
        const float* sc = up_src + (size_t)c * Hi * Wi;
        float v00 = sc[h0c * Wi + w0c], v01 = sc[h0c * Wi + w1c];
        float v10 = sc[h1c * Wi + w0c], v11 = sc[h1c * Wi + w1c];
        v = (1.0f - ah) * ((1.0f - aw) * v00 + aw * v01)
          + ah * ((1.0f - aw) * v10 + aw * v11);
    } else {
        v = skip[(size_t)(c - Cup) * Ho * Wo + h * Wo + w];
    }
    out[n] = v;
}

// ---------------------------------------------------------------------------
// Decoder split-K conv, TEMPLATED: CS channels/chunk, COG couts/thread.
// ---------------------------------------------------------------------------
template<int CIN, int CS, int COG>
__global__ void k_dconv(const float* __restrict__ in,
                        const float* __restrict__ wt,
                        float* __restrict__ part,
                        int Cout, int H, int W) {
    int HW  = H * W;
    int pix = blockIdx.x * blockDim.x + threadIdx.x;
    if (pix >= HW) return;
    int co0   = blockIdx.y * COG;
    int chunk = blockIdx.z;
    int h = pix / W, w = pix - h * W;

    int off[9]; float msk[9];
    #pragma unroll
    for (int kh = 0; kh < 3; kh++) {
        int r = h + kh - 1;
        bool rok = (r >= 0) && (r < H);
        int rc = rok ? r : 0;
        #pragma unroll
        for (int kw = 0; kw < 3; kw++) {
            int cc = w + kw - 1;
            bool cok = (cc >= 0) && (cc < W);
            int ccc = cok ? cc : 0;
            off[kh * 3 + kw] = rc * W + ccc;
            msk[kh * 3 + kw] = (rok && cok) ? 1.0f : 0.0f;
        }
    }

    const float* ibase = in + (size_t)chunk * CS * HW;
    const float* wbase = wt + ((size_t)co0 * CIN + (size_t)chunk * CS) * 9;

    float acc[COG];
    #pragma unroll
    for (int co = 0; co < COG; co++) acc[co] = 0.0f;

    #pragma unroll 8
    for (int ci = 0; ci < CS; ci++) {
        const float* ic = ibase + (size_t)ci * HW;
        float tap[9];
        #pragma unroll
        for (int j = 0; j < 9; j++)
            tap[j] = msk[j] * ic[off[j]];
        #pragma unroll
        for (int co = 0; co < COG; co++) {
            const float* wc = wbase + ((size_t)co * CIN + ci) * 9;
            #pragma unroll
            for (int j = 0; j < 9; j++)
                acc[co] = fmaf(tap[j], wc[j], acc[co]);
        }
    }

    float* pp = part + ((size_t)chunk * Cout + co0) * HW + pix;
    #pragma unroll
    for (int co = 0; co < COG; co++) pp[(size_t)co * HW] = acc[co];
}

__global__ void k_reduce_relu(const float* __restrict__ part,
                              const float* __restrict__ bias,
                              float* __restrict__ out,
                              int Cout, int HW, int nchunks) {
    int n = blockIdx.x * blockDim.x + threadIdx.x;
    if (n >= Cout * HW) return;
    int co = n / HW;
    float acc = bias[co];
    for (int c = 0; c < nchunks; c++)
        acc += part[(size_t)c * Cout * HW + n];
    out[n] = fmaxf(acc, 0.0f);
}

// ---------------------------------------------------------------------------
// Final: bilinear up d1 (post-ReLU) [8,50,184] -> (100,368), fused 1x1 conv.
// ---------------------------------------------------------------------------
__global__ void k_final(const float* __restrict__ d1,
                        const float* __restrict__ wo,
                        const float* __restrict__ bo,
                        float* __restrict__ out) {
    int n = blockIdx.x * blockDim.x + threadIdx.x;
    if (n >= 36800) return;
    int w = n % 368, h = n / 368;
    float ph = (h + 0.5f) * 0.5f - 0.5f;
    float pw = (w + 0.5f) * 0.5f - 0.5f;
    float fh = floorf(ph), fw = floorf(pw);
    int h0 = (int)fh, w0 = (int)fw;
    float ah = ph - fh, aw = pw - fw;
    int h0c = min(max(h0, 0), 49),  h1c = min(max(h0 + 1, 0), 49);
    int w0c = min(max(w0, 0), 183), w1c = min(max(w0 + 1, 0), 183);
    float acc = bo[0];
    #pragma unroll
    for (int c = 0; c < 8; c++) {
        const float* sc = d1 + c * 9200;
        float v00 = sc[h0c * 184 + w0c], v01 = sc[h0c * 184 + w1c];
        float v10 = sc[h1c * 184 + w0c], v11 = sc[h1c * 184 + w1c];
        float v = (1.0f - ah) * ((1.0f - aw) * v00 + aw * v01)
                + ah * ((1.0f - aw) * v10 + aw * v11);
        acc = fmaf(wo[c], v, acc);
    }
    out[n] = acc;
}

// ---------------------------------------------------------------------------
extern "C" void kernel_launch(void* const* d_in, const int* in_sizes, int n_in,
                              void* d_out, int out_size, void* d_ws, size_t ws_size,
                              hipStream_t stream) {
    (void)in_sizes; (void)n_in; (void)out_size; (void)ws_size;
    const float* x   = (const float*)d_in[0];
    const float* w1  = (const float*)d_in[1];
    const float* b1  = (const float*)d_in[2];
    const float* w2  = (const float*)d_in[3];
    const float* b2  = (const float*)d_in[4];
    const float* w3  = (const float*)d_in[5];
    const float* b3  = (const float*)d_in[6];
    const float* w4  = (const float*)d_in[7];
    const float* b4  = (const float*)d_in[8];
    const float* dw4 = (const float*)d_in[9];
    const float* db4 = (const float*)d_in[10];
    const float* dw3 = (const float*)d_in[11];
    const float* db3 = (const float*)d_in[12];
    const float* dw2 = (const float*)d_in[13];
    const float* db2 = (const float*)d_in[14];
    const float* dw1 = (const float*)d_in[15];
    const float* db1 = (const float*)d_in[16];
    const float* wo  = (const float*)d_in[17];
    const float* bo  = (const float*)d_in[18];
    float* out = (float*)d_out;

    // ---- workspace ----
    char* ws = (char*)d_ws;
    size_t off = 0;
    auto alloc = [&](size_t bytes) -> void* {
        void* p = ws + off;
        off += (bytes + 255) & ~(size_t)255;
        return p;
    };
    float*         cbuf  = (float*)alloc(147200000);          // conv buffer
    unsigned char* spk1p = (unsigned char*)alloc(39936000);   // [1000,4,52,192]
    unsigned char* spk2p = (unsigned char*)alloc(21600000);   // [1000,8,27,100]
    unsigned char* spk3p = (unsigned char*)alloc(12960000);   // [1000,16,15,54]
    float*         skip0 = (float*)alloc(2944000);            // [80,9200]
    float*         skip1 = (float*)alloc(1472000);            // [160,2300]
    float*         skip2 = (float*)alloc(765440);             // [320,598]
    float*         skip3 = (float*)alloc(412160);             // [640,161]
    float*         msS   = (float*)alloc(147200);             // scan scratch
    // decoder buffers alias cbuf (dead after encoder)
    char* dec = (char*)cbuf;
    size_t doff = 0;
    auto dalloc = [&](size_t bytes) -> void* {
        void* p = dec + doff;
        doff += (bytes + 255) & ~(size_t)255;
        return p;
    };
    float* d4   = (float*)dalloc(10304u * 4);                 // [64,161] post-ReLU
    float* d3   = (float*)dalloc(19136u * 4);                 // [32,598]
    float* d2   = (float*)dalloc(36800u * 4);                 // [16,2300]
    float* d1   = (float*)dalloc(73600u * 4);                 // [8,9200]
    float* cat3 = (float*)dalloc(229632u * 4);                // [384,598]
    float* cat2 = (float*)dalloc(441600u * 4);                // [192,2300]
    float* cat1 = (float*)dalloc(883200u * 4);                // [96,9200]
    float* part = (float*)dalloc(230400u * 4);                // split-K partials

    const int BS  = 256;
    const int SBS = 64;

    // zero ALL spike buffers in one contiguous coalesced fill (~11 us).
    // R1/R4/R5 halo-subset variants were slower: scattered byte stores are
    // 64B-line RMWs (~8x effective traffic) + extra launches.
    {
        size_t nb = 39936000ull + 21600000 + 12960000;
        int n16 = (int)(nb / 16);
        k_zero16<<<CDIV(n16, BS), BS, 0, stream>>>((float4*)spk1p, n16);
    }

    // ---- encoder ----
    k_conv1<<<CDIV(1000 * 50 * 46, BS), BS, 0, stream>>>(x, w1, b1, cbuf);
    k_scan<<<CDIV(36800, SBS), SBS, 0, stream>>>(cbuf, spk1p, skip0, msS,
                                                 4, 9200, 184, 192, 52 * 192, 1);

    k_convs2<4, 8, 8, 4, 25, 92, 0, 52, 192>
        <<<dim3(CDIV(1000 * 25 * 23, BS), 1), BS, 0, stream>>>(spk1p, w2, b2, cbuf);
    k_scan<<<CDIV(18400, SBS), SBS, 0, stream>>>(cbuf, spk2p, skip1, msS,
                                                 8, 2300, 92, 100, 27 * 100, 1);

    k_convs2<8, 16, 16, 2, 13, 46, 1, 27, 100>
        <<<dim3(CDIV(1000 * 13 * 23, BS), 1), BS, 0, stream>>>(spk2p, w3, b3, cbuf);
    k_scan<<<CDIV(9568, SBS), SBS, 0, stream>>>(cbuf, spk3p, skip2, msS,
                                                16, 598, 46, 54, 15 * 54, 1);

    k_convs2<16, 32, 16, 2, 7, 23, 1, 15, 54>
        <<<dim3(CDIV(1000 * 7 * 12, BS), 2), BS, 0, stream>>>(spk3p, w4, b4, cbuf);
    k_scan<<<CDIV(5152, SBS), SBS, 0, stream>>>(cbuf, spk1p /*unused*/, skip3, msS,
                                                32, 161, 23, 31, 9 * 31, 0);

    // ---- decoder: up_cat + templated split-K conv + reduce ----
    {   // L4: skip3[640,7,23] -> d4[64,161]; CS=32 (20 chunks), COG=4
        dim3 g(CDIV(161, 64), 16, 20);
        k_dconv<640, 32, 4><<<g, 64, 0, stream>>>(skip3, dw4, part, 64, 7, 23);
        k_reduce_relu<<<CDIV(64 * 161, BS), BS, 0, stream>>>(part, db4, d4, 64, 161, 20);
    }
    {   // L3: cat3=[up(d4),64|skip2,320] -> d3[32,598]; CS=32 (12), COG=4
        k_up_cat<<<CDIV(384 * 598, BS), BS, 0, stream>>>(d4, 64, 7, 23,
                                                         skip2, 320, cat3, 13, 46);
        dim3 g(CDIV(598, 64), 8, 12);
        k_dconv<384, 32, 4><<<g, 64, 0, stream>>>(cat3, dw3, part, 32, 13, 46);
        k_reduce_relu<<<CDIV(32 * 598, BS), BS, 0, stream>>>(part, db3, d3, 32, 598, 12);
    }
    {   // L2: cat2=[up(d3),32|skip1,160] -> d2[16,2300]; CS=32 (6), COG=4
        k_up_cat<<<CDIV(192 * 2300, BS), BS, 0, stream>>>(d3, 32, 13, 46,
                                                          skip1, 160, cat2, 25, 92);
        dim3 g(CDIV(2300, 128), 4, 6);
        k_dconv<192, 32, 4><<<g, 128, 0, stream>>>(cat2, dw2, part, 16, 25, 92);
        k_reduce_relu<<<CDIV(16 * 2300, BS), BS, 0, stream>>>(part, db2, d2, 16, 2300, 6);
    }
    {   // L1: cat1=[up(d2),16|skip0,80] -> d1[8,9200]; CS=32 (3), COG=4
        k_up_cat<<<CDIV(96 * 9200, BS), BS, 0, stream>>>(d2, 16, 25, 92,
                                                         skip0, 80, cat1, 50, 184);
        dim3 g(CDIV(9200, BS), 2, 3);
        k_dconv<96, 32, 4><<<g, BS, 0, stream>>>(cat1, dw1, part, 8, 50, 184);
        k_reduce_relu<<<CDIV(8 * 9200, BS), BS, 0, stream>>>(part, db1, d1, 8, 9200, 3);
    }
    k_final<<<CDIV(36800, BS), BS, 0, stream>>>(d1, wo, bo, out);
}